// Round 1
// baseline (510.599 us; speedup 1.0000x reference)
//
#include <hip/hip_runtime.h>

#define IN_C 512
#define OUT_C 1024
#define NC2 2048
#define NEG_SLOPE 0.2f

typedef short frag8 __attribute__((ext_vector_type(8)));
typedef float f32x4 __attribute__((ext_vector_type(4)));

__device__ __forceinline__ unsigned short f2b(float f){
  unsigned u = __float_as_uint(f);
  unsigned r = (u + 0x7fffu + ((u >> 16) & 1u)) >> 16;
  return (unsigned short)r;
}
__device__ __forceinline__ float b2f(unsigned short s){
  return __uint_as_float(((unsigned)s) << 16);
}
__device__ __forceinline__ unsigned encf(float f){
  unsigned u = __float_as_uint(f);
  return (u & 0x80000000u) ? ~u : (u | 0x80000000u);
}
__device__ __forceinline__ float decf(unsigned u){
  unsigned v = (u & 0x80000000u) ? (u & 0x7fffffffu) : ~u;
  return __uint_as_float(v);
}
__device__ __forceinline__ float leaky(float v){ return v >= 0.f ? v : NEG_SLOPE * v; }

// ---------------- conversion / transpose ----------------

__global__ void cvt_x_kernel(const float* __restrict__ x, unsigned short* __restrict__ xb, int total4){
  int i = blockIdx.x * 256 + threadIdx.x;
  if (i >= total4) return;
  float4 v = ((const float4*)x)[i];
  ushort4 o;
  o.x = f2b(v.x); o.y = f2b(v.y); o.z = f2b(v.z); o.w = f2b(v.w);
  ((ushort4*)xb)[i] = o;
}

// out[(c + rowOff)][r] = bf16(in[r][c]); in is R x C (both multiples of 32), out row stride R
__global__ void transpose_cvt_kernel(const float* __restrict__ in, unsigned short* __restrict__ out,
                                     int R, int C, int rowOff){
  __shared__ float tile[32][33];
  int c0 = blockIdx.x * 32, r0 = blockIdx.y * 32;
  for (int i = threadIdx.y; i < 32; i += 8)
    tile[i][threadIdx.x] = in[(size_t)(r0 + i) * C + c0 + threadIdx.x];
  __syncthreads();
  for (int i = threadIdx.y; i < 32; i += 8)
    out[(size_t)(c0 + i + rowOff) * R + r0 + threadIdx.x] = f2b(tile[threadIdx.x][i]);
}

// ---------------- attention-logit precompute ----------------

// uv[which][i] = sum_j W[i][j] * a[j], which in {0:W1@a_src1, 1:W1@a_dst1, 2:W2@a_src2, 3:W2@a_dst2}
__global__ void uv_kernel(const float* __restrict__ W1, const float* __restrict__ W2,
                          const float* __restrict__ a_src1, const float* __restrict__ a_dst1,
                          const float* __restrict__ a_src2, const float* __restrict__ a_dst2,
                          float* __restrict__ uv){
  int g = blockIdx.x * 4 + (threadIdx.x >> 6);
  int lane = threadIdx.x & 63;
  int which = g >> 9;
  int i = g & 511;
  const float* W = (which < 2) ? W1 : W2;
  const float* a = (which == 0) ? a_src1 : (which == 1) ? a_dst1 : (which == 2) ? a_src2 : a_dst2;
  const float* row = W + (size_t)i * OUT_C;
  float s = 0.f;
  for (int j = lane; j < OUT_C; j += 64) s += row[j] * a[j];
  for (int off = 32; off; off >>= 1) s += __shfl_down(s, off);
  if (lane == 0) uv[which * IN_C + i] = s;
}

// per-node alphas: wave w of each block computes dot(x[n], uv[w])
__global__ void alpha_kernel(const float* __restrict__ x, const float* __restrict__ uv,
                             float* __restrict__ as1, float* __restrict__ ad1,
                             float* __restrict__ as2, float* __restrict__ ad2){
  int n = blockIdx.x;
  int w = threadIdx.x >> 6, lane = threadIdx.x & 63;
  const float* row = x + (size_t)n * IN_C;
  const float* u = uv + w * IN_C;
  float s = 0.f;
  for (int j = lane; j < IN_C; j += 64) s += row[j] * u[j];
  for (int off = 32; off; off >>= 1) s += __shfl_down(s, off);
  if (lane == 0){
    if (w == 0) as1[n] = s;
    else if (w == 1) ad1[n] = s;
    else if (w == 2) as2[n] = s;
    else ad2[n] = s;
  }
}

// ---------------- CSR build ----------------

__global__ void zero_kernel(int* counts, int* cursor, float* colsum, int N){
  int i = blockIdx.x * 256 + threadIdx.x;
  if (i < N){ counts[i] = 0; cursor[i] = 0; }
  if (i < OUT_C) colsum[i] = 0.f;
}

__global__ void hist_kernel(const int* __restrict__ dst, int* counts, int E){
  int e = blockIdx.x * 256 + threadIdx.x;
  if (e < E) atomicAdd(&counts[dst[e]], 1);
}

__global__ void scan_kernel(const int* __restrict__ counts, int* __restrict__ offs, int n){
  __shared__ int buf[256];
  __shared__ int carry;
  if (threadIdx.x == 0) carry = 0;
  __syncthreads();
  for (int base = 0; base < n; base += 256){
    int i = base + threadIdx.x;
    int v = (i < n) ? counts[i] : 0;
    buf[threadIdx.x] = v;
    __syncthreads();
    for (int o = 1; o < 256; o <<= 1){
      int t = (threadIdx.x >= o) ? buf[threadIdx.x - o] : 0;
      __syncthreads();
      buf[threadIdx.x] += t;
      __syncthreads();
    }
    if (i < n) offs[i] = carry + buf[threadIdx.x] - v;
    __syncthreads();
    if (threadIdx.x == 0) carry += buf[255];
    __syncthreads();
  }
}

__global__ void scatter_kernel(const int* __restrict__ dst, const int* __restrict__ offs,
                               int* cursor, int* __restrict__ csr, int E){
  int e = blockIdx.x * 256 + threadIdx.x;
  if (e < E){
    int d = dst[e];
    int p = atomicAdd(&cursor[d], 1);
    csr[offs[d] + p] = e;
  }
}

// ---------------- edge softmax ----------------

__global__ void selfinit_kernel(const float* __restrict__ as1, const float* __restrict__ ad1,
                                const float* __restrict__ as2, const float* __restrict__ ad2,
                                float* __restrict__ self1, float* __restrict__ self2,
                                unsigned* __restrict__ m1e, unsigned* __restrict__ m2e, int N){
  int i = blockIdx.x * 256 + threadIdx.x;
  if (i >= N) return;
  float e1 = leaky(as1[i] + ad1[i]);
  float e2 = leaky(as2[i] + ad2[i]);
  self1[i] = e1; self2[i] = e2;
  m1e[i] = encf(e1); m2e[i] = encf(e2);
}

__global__ void edgemax_kernel(const int* __restrict__ src, const int* __restrict__ dst,
                               const float* __restrict__ as1, const float* __restrict__ ad1,
                               const float* __restrict__ as2, const float* __restrict__ ad2,
                               unsigned* m1e, unsigned* m2e, int E){
  int e = blockIdx.x * 256 + threadIdx.x;
  if (e >= E) return;
  int s = src[e], d = dst[e];
  atomicMax(&m1e[d], encf(leaky(as1[s] + ad1[d])));
  atomicMax(&m2e[d], encf(leaky(as2[s] + ad2[d])));
}

__global__ void denominit_kernel(const unsigned* __restrict__ m1e, const unsigned* __restrict__ m2e,
                                 const float* __restrict__ self1, const float* __restrict__ self2,
                                 float* __restrict__ m1, float* __restrict__ m2,
                                 float* __restrict__ den1, float* __restrict__ den2, int N){
  int i = blockIdx.x * 256 + threadIdx.x;
  if (i >= N) return;
  float a = decf(m1e[i]), b = decf(m2e[i]);
  m1[i] = a; m2[i] = b;
  den1[i] = expf(self1[i] - a);
  den2[i] = expf(self2[i] - b);
}

__global__ void edgeexp_kernel(const int* __restrict__ src, const int* __restrict__ dst,
                               const float* __restrict__ as1, const float* __restrict__ ad1,
                               const float* __restrict__ as2, const float* __restrict__ ad2,
                               const float* __restrict__ m1, const float* __restrict__ m2,
                               float* __restrict__ ex1, float* __restrict__ ex2,
                               float* den1, float* den2, int E){
  int e = blockIdx.x * 256 + threadIdx.x;
  if (e >= E) return;
  int s = src[e], d = dst[e];
  float x1 = expf(leaky(as1[s] + ad1[d]) - m1[d]);
  float x2 = expf(leaky(as2[s] + ad2[d]) - m2[d]);
  ex1[e] = x1; ex2[e] = x2;
  atomicAdd(&den1[d], x1);
  atomicAdd(&den2[d], x2);
}

// ---------------- GEMM1: H[M][2048] = x_bf16[M][512] @ WcatT[2048][512]^T ----------------

__global__ __launch_bounds__(256) void gemm1_kernel(const unsigned short* __restrict__ A,
                                                    const unsigned short* __restrict__ BT,
                                                    unsigned short* __restrict__ H, int M){
  __shared__ unsigned short Al[128][40];
  __shared__ unsigned short Bl[128][40];
  const int t = threadIdx.x;
  const int lane = t & 63, wid = t >> 6;
  const int wi = wid & 1, wj = wid >> 1;
  const int l16 = lane & 15, q = lane >> 4;
  const int bm = blockIdx.y * 128, bn = blockIdx.x * 128;
  const int arow = t >> 1, acolh = (t & 1) * 16;
  f32x4 acc[4][4] = {};
  for (int k0 = 0; k0 < IN_C; k0 += 32){
    int gr = bm + arow;
    int4 v0 = {0,0,0,0}, v1 = {0,0,0,0};
    if (gr < M){
      const int4* p = (const int4*)(A + (size_t)gr * IN_C + k0 + acolh);
      v0 = p[0]; v1 = p[1];
    }
    *(int4*)&Al[arow][acolh] = v0;
    *(int4*)&Al[arow][acolh + 8] = v1;
    const int4* pb = (const int4*)(BT + (size_t)(bn + arow) * IN_C + k0 + acolh);
    *(int4*)&Bl[arow][acolh] = pb[0];
    *(int4*)&Bl[arow][acolh + 8] = pb[1];
    __syncthreads();
    frag8 af[4], bf[4];
#pragma unroll
    for (int mi = 0; mi < 4; mi++) af[mi] = *(const frag8*)&Al[wi*64 + mi*16 + l16][q*8];
#pragma unroll
    for (int nj = 0; nj < 4; nj++) bf[nj] = *(const frag8*)&Bl[wj*64 + nj*16 + l16][q*8];
#pragma unroll
    for (int mi = 0; mi < 4; mi++)
#pragma unroll
      for (int nj = 0; nj < 4; nj++)
        acc[mi][nj] = __builtin_amdgcn_mfma_f32_16x16x32_bf16(af[mi], bf[nj], acc[mi][nj], 0, 0, 0);
    __syncthreads();
  }
#pragma unroll
  for (int mi = 0; mi < 4; mi++){
#pragma unroll
    for (int r = 0; r < 4; r++){
      int row = bm + wi*64 + mi*16 + q*4 + r;
      if (row >= M) continue;
#pragma unroll
      for (int nj = 0; nj < 4; nj++){
        int col = bn + wj*64 + nj*16 + l16;
        H[(size_t)row * NC2 + col] = f2b(acc[mi][nj][r]);
      }
    }
  }
}

// ---------------- GEMM2: colsum += sum_rows tanh(hsum @ Wp1 + bp1) ----------------

__global__ __launch_bounds__(256) void gemm2_kernel(const unsigned short* __restrict__ A,
                                                    const unsigned short* __restrict__ BT,
                                                    const float* __restrict__ bp1,
                                                    float* __restrict__ colsum, int M){
  __shared__ unsigned short Al[128][40];
  __shared__ unsigned short Bl[128][40];
  __shared__ float cs[128];
  const int t = threadIdx.x;
  const int lane = t & 63, wid = t >> 6;
  const int wi = wid & 1, wj = wid >> 1;
  const int l16 = lane & 15, q = lane >> 4;
  const int bm = blockIdx.y * 128, bn = blockIdx.x * 128;
  const int arow = t >> 1, acolh = (t & 1) * 16;
  if (t < 128) cs[t] = 0.f;
  f32x4 acc[4][4] = {};
  for (int k0 = 0; k0 < OUT_C; k0 += 32){
    int gr = bm + arow;
    int4 v0 = {0,0,0,0}, v1 = {0,0,0,0};
    if (gr < M){
      const int4* p = (const int4*)(A + (size_t)gr * OUT_C + k0 + acolh);
      v0 = p[0]; v1 = p[1];
    }
    *(int4*)&Al[arow][acolh] = v0;
    *(int4*)&Al[arow][acolh + 8] = v1;
    const int4* pb = (const int4*)(BT + (size_t)(bn + arow) * OUT_C + k0 + acolh);
    *(int4*)&Bl[arow][acolh] = pb[0];
    *(int4*)&Bl[arow][acolh + 8] = pb[1];
    __syncthreads();
    frag8 af[4], bf[4];
#pragma unroll
    for (int mi = 0; mi < 4; mi++) af[mi] = *(const frag8*)&Al[wi*64 + mi*16 + l16][q*8];
#pragma unroll
    for (int nj = 0; nj < 4; nj++) bf[nj] = *(const frag8*)&Bl[wj*64 + nj*16 + l16][q*8];
#pragma unroll
    for (int mi = 0; mi < 4; mi++)
#pragma unroll
      for (int nj = 0; nj < 4; nj++)
        acc[mi][nj] = __builtin_amdgcn_mfma_f32_16x16x32_bf16(af[mi], bf[nj], acc[mi][nj], 0, 0, 0);
    __syncthreads();
  }
#pragma unroll
  for (int nj = 0; nj < 4; nj++){
    int col = bn + wj*64 + nj*16 + l16;
    float bias = bp1[col];
    float p = 0.f;
#pragma unroll
    for (int mi = 0; mi < 4; mi++){
#pragma unroll
      for (int r = 0; r < 4; r++){
        int row = bm + wi*64 + mi*16 + q*4 + r;
        float tv = tanhf(acc[mi][nj][r] + bias);
        if (row < M) p += tv;
      }
    }
    p += __shfl_xor(p, 16);
    p += __shfl_xor(p, 32);
    if (q == 0) atomicAdd(&cs[wj*64 + nj*16 + l16], p);
  }
  __syncthreads();
  if (t < 128) atomicAdd(&colsum[bn + t], cs[t]);
}

// ---------------- aggregation: one block per dst node ----------------

__global__ __launch_bounds__(256) void agg_kernel(
    const int* __restrict__ srcArr, const int* __restrict__ counts, const int* __restrict__ offs,
    const int* __restrict__ csr, const float* __restrict__ ex1, const float* __restrict__ ex2,
    const float* __restrict__ den1, const float* __restrict__ den2,
    const float* __restrict__ self1, const float* __restrict__ self2,
    const float* __restrict__ m1, const float* __restrict__ m2,
    const unsigned short* __restrict__ H,
    const float* __restrict__ b1, const float* __restrict__ b2, const float* __restrict__ prelu_a,
    float* __restrict__ hout1, float* __restrict__ hout2, unsigned short* __restrict__ hsum){
  int d = blockIdx.x;
  int tid = threadIdx.x;
  __shared__ int s_l[256];
  __shared__ float w1_l[256], w2_l[256];
  float inv1 = 1.f / den1[d], inv2 = 1.f / den2[d];
  int deg = counts[d], off = offs[d];
  float acc1[4] = {0,0,0,0}, acc2[4] = {0,0,0,0};
  int cbase = tid * 4;
  for (int base = 0; base < deg; base += 256){
    int i = base + tid;
    if (i < deg){
      int e = csr[off + i];
      s_l[tid] = srcArr[e];
      w1_l[tid] = ex1[e] * inv1;
      w2_l[tid] = ex2[e] * inv2;
    }
    __syncthreads();
    int cnt = min(256, deg - base);
    for (int j = 0; j < cnt; j++){
      int s = s_l[j];
      float w1 = w1_l[j], w2 = w2_l[j];
      const unsigned short* hp = H + (size_t)s * NC2 + cbase;
      ushort4 u1 = *(const ushort4*)hp;
      ushort4 u2 = *(const ushort4*)(hp + OUT_C);
      acc1[0] += w1 * b2f(u1.x); acc1[1] += w1 * b2f(u1.y);
      acc1[2] += w1 * b2f(u1.z); acc1[3] += w1 * b2f(u1.w);
      acc2[0] += w2 * b2f(u2.x); acc2[1] += w2 * b2f(u2.y);
      acc2[2] += w2 * b2f(u2.z); acc2[3] += w2 * b2f(u2.w);
    }
    __syncthreads();
  }
  // self loop
  {
    float ws1 = expf(self1[d] - m1[d]) * inv1;
    float ws2 = expf(self2[d] - m2[d]) * inv2;
    const unsigned short* hp = H + (size_t)d * NC2 + cbase;
    ushort4 u1 = *(const ushort4*)hp;
    ushort4 u2 = *(const ushort4*)(hp + OUT_C);
    acc1[0] += ws1 * b2f(u1.x); acc1[1] += ws1 * b2f(u1.y);
    acc1[2] += ws1 * b2f(u1.z); acc1[3] += ws1 * b2f(u1.w);
    acc2[0] += ws2 * b2f(u2.x); acc2[1] += ws2 * b2f(u2.y);
    acc2[2] += ws2 * b2f(u2.z); acc2[3] += ws2 * b2f(u2.w);
  }
  float pa = prelu_a[0];
  float4 bb1 = *(const float4*)(b1 + cbase);
  float4 bb2 = *(const float4*)(b2 + cbase);
  float o1[4], o2[4];
  o1[0] = acc1[0] + bb1.x; o1[1] = acc1[1] + bb1.y; o1[2] = acc1[2] + bb1.z; o1[3] = acc1[3] + bb1.w;
  o2[0] = acc2[0] + bb2.x; o2[1] = acc2[1] + bb2.y; o2[2] = acc2[2] + bb2.z; o2[3] = acc2[3] + bb2.w;
#pragma unroll
  for (int r = 0; r < 4; r++){
    o1[r] = o1[r] >= 0.f ? o1[r] : pa * o1[r];
    o2[r] = o2[r] >= 0.f ? o2[r] : pa * o2[r];
  }
  float4 f1; f1.x = o1[0]; f1.y = o1[1]; f1.z = o1[2]; f1.w = o1[3];
  float4 f2v; f2v.x = o2[0]; f2v.y = o2[1]; f2v.z = o2[2]; f2v.w = o2[3];
  *(float4*)(hout1 + (size_t)d * OUT_C + cbase) = f1;
  *(float4*)(hout2 + (size_t)d * OUT_C + cbase) = f2v;
  ushort4 hs;
  hs.x = f2b(o1[0] + o2[0]); hs.y = f2b(o1[1] + o2[1]);
  hs.z = f2b(o1[2] + o2[2]); hs.w = f2b(o1[3] + o2[3]);
  *(ushort4*)(hsum + (size_t)d * OUT_C + cbase) = hs;
}

// ---------------- semantic attention tail ----------------

__global__ void wproj_kernel(const float* __restrict__ colsum, const float* __restrict__ Wp2,
                             float* __restrict__ wv, float invN){
  int o = blockIdx.x * 256 + threadIdx.x;
  float acc = 0.f;
  for (int c = 0; c < OUT_C; c++) acc += colsum[c] * Wp2[(size_t)c * OUT_C + o];
  wv[o] = acc * invN;
}

__global__ __launch_bounds__(1024) void softmax_kernel(const float* __restrict__ wv, float* __restrict__ att){
  int o = threadIdx.x;
  __shared__ float red[1024];
  float w = wv[o];
  red[o] = w; __syncthreads();
  for (int s = 512; s > 0; s >>= 1){ if (o < s) red[o] = fmaxf(red[o], red[o + s]); __syncthreads(); }
  float m = red[0]; __syncthreads();
  float e = expf(w - m);
  red[o] = e; __syncthreads();
  for (int s = 512; s > 0; s >>= 1){ if (o < s) red[o] += red[o + s]; __syncthreads(); }
  att[o] = e / red[0];
}

__global__ void combine_kernel(const float* __restrict__ att, const float* h1,
                               const float* __restrict__ h2, float* out, int total4){
  int i = blockIdx.x * 256 + threadIdx.x;
  if (i >= total4) return;
  float4 a = ((const float4*)att)[i & 255];
  float4 v1 = ((const float4*)h1)[i];
  float4 v2 = ((const float4*)h2)[i];
  float4 o;
  o.x = a.x * v1.x + (1.f - a.x) * v2.x;
  o.y = a.y * v1.y + (1.f - a.y) * v2.y;
  o.z = a.z * v1.z + (1.f - a.z) * v2.z;
  o.w = a.w * v1.w + (1.f - a.w) * v2.w;
  ((float4*)out)[i] = o;
}

// ---------------- launch ----------------

extern "C" void kernel_launch(void* const* d_in, const int* in_sizes, int n_in,
                              void* d_out, int out_size, void* d_ws, size_t ws_size,
                              hipStream_t stream){
  const float* x      = (const float*)d_in[0];
  const int*   edge   = (const int*)d_in[1];
  const float* W1     = (const float*)d_in[2];
  const float* a_src1 = (const float*)d_in[3];
  const float* a_dst1 = (const float*)d_in[4];
  const float* b1     = (const float*)d_in[5];
  const float* W2     = (const float*)d_in[6];
  const float* a_src2 = (const float*)d_in[7];
  const float* a_dst2 = (const float*)d_in[8];
  const float* b2     = (const float*)d_in[9];
  const float* prelu_a= (const float*)d_in[10];
  const float* Wp1    = (const float*)d_in[11];
  const float* bp1    = (const float*)d_in[12];
  const float* Wp2    = (const float*)d_in[13];
  const int N = in_sizes[0] / IN_C;
  const int E = in_sizes[1] / 2;
  const int* srcArr = edge;
  const int* dstArr = edge + E;

  char* ws = (char*)d_ws;
  size_t o = 0;
  auto alloc = [&](size_t b) -> char* {
    char* p = ws + o;
    o = (o + b + 255) & ~(size_t)255;
    return p;
  };
  unsigned short* xb    = (unsigned short*)alloc((size_t)N * IN_C * 2);
  unsigned short* WT    = (unsigned short*)alloc((size_t)NC2 * IN_C * 2);
  unsigned short* Wp1T  = (unsigned short*)alloc((size_t)OUT_C * OUT_C * 2);
  unsigned short* H     = (unsigned short*)alloc((size_t)N * NC2 * 2);
  float*          hout2 = (float*)alloc((size_t)N * OUT_C * 4);
  unsigned short* hsum  = (unsigned short*)alloc((size_t)N * OUT_C * 2);
  float*          uv    = (float*)alloc(4 * IN_C * 4);
  float*          as1   = (float*)alloc((size_t)4 * N * 4);
  float* ad1 = as1 + N; float* as2 = as1 + 2 * N; float* ad2 = as1 + 3 * N;
  float*          self1 = (float*)alloc((size_t)2 * N * 4); float* self2 = self1 + N;
  unsigned*       m1e   = (unsigned*)alloc((size_t)2 * N * 4); unsigned* m2e = m1e + N;
  float*          m1    = (float*)alloc((size_t)2 * N * 4); float* m2 = m1 + N;
  float*          den1  = (float*)alloc((size_t)2 * N * 4); float* den2 = den1 + N;
  float*          ex1   = (float*)alloc((size_t)2 * E * 4); float* ex2 = ex1 + E;
  int*            counts= (int*)alloc((size_t)N * 4);
  int*            offs  = (int*)alloc((size_t)(N + 1) * 4);
  int*            cursor= (int*)alloc((size_t)N * 4);
  int*            csr   = (int*)alloc((size_t)E * 4);
  float*          colsum= (float*)alloc(OUT_C * 4);
  float*          wv    = (float*)alloc(OUT_C * 4);
  float*          att   = (float*)alloc(OUT_C * 4);
  float* hout1 = (float*)d_out;

  dim3 tb(32, 8);
  cvt_x_kernel<<<(N * IN_C / 4 + 255) / 256, 256, 0, stream>>>(x, xb, N * IN_C / 4);
  transpose_cvt_kernel<<<dim3(OUT_C / 32, IN_C / 32), tb, 0, stream>>>(W1, WT, IN_C, OUT_C, 0);
  transpose_cvt_kernel<<<dim3(OUT_C / 32, IN_C / 32), tb, 0, stream>>>(W2, WT, IN_C, OUT_C, OUT_C);
  transpose_cvt_kernel<<<dim3(OUT_C / 32, OUT_C / 32), tb, 0, stream>>>(Wp1, Wp1T, OUT_C, OUT_C, 0);
  uv_kernel<<<512, 256, 0, stream>>>(W1, W2, a_src1, a_dst1, a_src2, a_dst2, uv);
  alpha_kernel<<<N, 256, 0, stream>>>(x, uv, as1, ad1, as2, ad2);
  zero_kernel<<<(N + 255) / 256, 256, 0, stream>>>(counts, cursor, colsum, N);
  hist_kernel<<<(E + 255) / 256, 256, 0, stream>>>(dstArr, counts, E);
  scan_kernel<<<1, 256, 0, stream>>>(counts, offs, N);
  scatter_kernel<<<(E + 255) / 256, 256, 0, stream>>>(dstArr, offs, cursor, csr, E);
  selfinit_kernel<<<(N + 255) / 256, 256, 0, stream>>>(as1, ad1, as2, ad2, self1, self2, m1e, m2e, N);
  edgemax_kernel<<<(E + 255) / 256, 256, 0, stream>>>(srcArr, dstArr, as1, ad1, as2, ad2, m1e, m2e, E);
  denominit_kernel<<<(N + 255) / 256, 256, 0, stream>>>(m1e, m2e, self1, self2, m1, m2, den1, den2, N);
  edgeexp_kernel<<<(E + 255) / 256, 256, 0, stream>>>(srcArr, dstArr, as1, ad1, as2, ad2, m1, m2, ex1, ex2, den1, den2, E);
  gemm1_kernel<<<dim3(NC2 / 128, (N + 127) / 128), 256, 0, stream>>>(xb, WT, H, N);
  agg_kernel<<<N, 256, 0, stream>>>(srcArr, counts, offs, csr, ex1, ex2, den1, den2,
                                    self1, self2, m1, m2, H, b1, b2, prelu_a, hout1, hout2, hsum);
  gemm2_kernel<<<dim3(OUT_C / 128, (N + 127) / 128), 256, 0, stream>>>(hsum, Wp1T, bp1, colsum, N);
  wproj_kernel<<<4, 256, 0, stream>>>(colsum, Wp2, wv, 1.0f / (float)N);
  softmax_kernel<<<1, 1024, 0, stream>>>(wv, att);
  combine_kernel<<<(N * OUT_C / 4 + 255) / 256, 256, 0, stream>>>(att, hout1, hout2, (float*)d_out, N * OUT_C / 4);
}

// Round 2
// 479.220 us; speedup vs baseline: 1.0655x; 1.0655x over previous
//
#include <hip/hip_runtime.h>

#define IN_C 512
#define OUT_C 1024
#define NC2 2048
#define NEG_SLOPE 0.2f

typedef short frag8 __attribute__((ext_vector_type(8)));
typedef float f32x4 __attribute__((ext_vector_type(4)));

#define GLOAD_LDS16(g, l) __builtin_amdgcn_global_load_lds(\
    (const __attribute__((address_space(1))) void*)(g), \
    (__attribute__((address_space(3))) void*)(l), 16, 0, 0)

__device__ __forceinline__ unsigned short f2b(float f){
  unsigned u = __float_as_uint(f);
  unsigned r = (u + 0x7fffu + ((u >> 16) & 1u)) >> 16;
  return (unsigned short)r;
}
__device__ __forceinline__ float b2f(unsigned short s){
  return __uint_as_float(((unsigned)s) << 16);
}
__device__ __forceinline__ unsigned encf(float f){
  unsigned u = __float_as_uint(f);
  return (u & 0x80000000u) ? ~u : (u | 0x80000000u);
}
__device__ __forceinline__ float decf(unsigned u){
  unsigned v = (u & 0x80000000u) ? (u & 0x7fffffffu) : ~u;
  return __uint_as_float(v);
}
__device__ __forceinline__ float leaky(float v){ return v >= 0.f ? v : NEG_SLOPE * v; }

// ---------------- conversion / transpose ----------------

__global__ void cvt_x_kernel(const float* __restrict__ x, unsigned short* __restrict__ xb, int total4){
  int i = blockIdx.x * 256 + threadIdx.x;
  if (i >= total4) return;
  float4 v = ((const float4*)x)[i];
  ushort4 o;
  o.x = f2b(v.x); o.y = f2b(v.y); o.z = f2b(v.z); o.w = f2b(v.w);
  ((ushort4*)xb)[i] = o;
}

// out[(c + rowOff)][r] = bf16(in[r][c]); in is R x C (both multiples of 32), out row stride R
__global__ void transpose_cvt_kernel(const float* __restrict__ in, unsigned short* __restrict__ out,
                                     int R, int C, int rowOff){
  __shared__ float tile[32][33];
  int c0 = blockIdx.x * 32, r0 = blockIdx.y * 32;
  for (int i = threadIdx.y; i < 32; i += 8)
    tile[i][threadIdx.x] = in[(size_t)(r0 + i) * C + c0 + threadIdx.x];
  __syncthreads();
  for (int i = threadIdx.y; i < 32; i += 8)
    out[(size_t)(c0 + i + rowOff) * R + r0 + threadIdx.x] = f2b(tile[threadIdx.x][i]);
}

// ---------------- attention-logit precompute ----------------

__global__ void uv_kernel(const float* __restrict__ W1, const float* __restrict__ W2,
                          const float* __restrict__ a_src1, const float* __restrict__ a_dst1,
                          const float* __restrict__ a_src2, const float* __restrict__ a_dst2,
                          float* __restrict__ uv){
  int g = blockIdx.x * 4 + (threadIdx.x >> 6);
  int lane = threadIdx.x & 63;
  int which = g >> 9;
  int i = g & 511;
  const float* W = (which < 2) ? W1 : W2;
  const float* a = (which == 0) ? a_src1 : (which == 1) ? a_dst1 : (which == 2) ? a_src2 : a_dst2;
  const float* row = W + (size_t)i * OUT_C;
  float s = 0.f;
  for (int j = lane; j < OUT_C; j += 64) s += row[j] * a[j];
  for (int off = 32; off; off >>= 1) s += __shfl_down(s, off);
  if (lane == 0) uv[which * IN_C + i] = s;
}

__global__ void alpha_kernel(const float* __restrict__ x, const float* __restrict__ uv,
                             float* __restrict__ as1, float* __restrict__ ad1,
                             float* __restrict__ as2, float* __restrict__ ad2){
  int n = blockIdx.x;
  int w = threadIdx.x >> 6, lane = threadIdx.x & 63;
  const float* row = x + (size_t)n * IN_C;
  const float* u = uv + w * IN_C;
  float s = 0.f;
  for (int j = lane; j < IN_C; j += 64) s += row[j] * u[j];
  for (int off = 32; off; off >>= 1) s += __shfl_down(s, off);
  if (lane == 0){
    if (w == 0) as1[n] = s;
    else if (w == 1) ad1[n] = s;
    else if (w == 2) as2[n] = s;
    else ad2[n] = s;
  }
}

// ---------------- CSR build ----------------

__global__ void zero_kernel(int* counts, int* cursor, float* colsum, int N){
  int i = blockIdx.x * 256 + threadIdx.x;
  if (i < N){ counts[i] = 0; cursor[i] = 0; }
  if (i < OUT_C) colsum[i] = 0.f;
}

__global__ void hist_kernel(const int* __restrict__ dst, int* counts, int E){
  int e = blockIdx.x * 256 + threadIdx.x;
  if (e < E) atomicAdd(&counts[dst[e]], 1);
}

__global__ void scan_kernel(const int* __restrict__ counts, int* __restrict__ offs, int n){
  __shared__ int buf[256];
  __shared__ int carry;
  if (threadIdx.x == 0) carry = 0;
  __syncthreads();
  for (int base = 0; base < n; base += 256){
    int i = base + threadIdx.x;
    int v = (i < n) ? counts[i] : 0;
    buf[threadIdx.x] = v;
    __syncthreads();
    for (int o = 1; o < 256; o <<= 1){
      int t = (threadIdx.x >= o) ? buf[threadIdx.x - o] : 0;
      __syncthreads();
      buf[threadIdx.x] += t;
      __syncthreads();
    }
    if (i < n) offs[i] = carry + buf[threadIdx.x] - v;
    __syncthreads();
    if (threadIdx.x == 0) carry += buf[255];
    __syncthreads();
  }
}

// pose[e] = CSR position of edge e (dst-bucketed)
__global__ void scatter_kernel(const int* __restrict__ dst, const int* __restrict__ offs,
                               int* cursor, int* __restrict__ pose, int E){
  int e = blockIdx.x * 256 + threadIdx.x;
  if (e < E){
    int d = dst[e];
    int p = atomicAdd(&cursor[d], 1);
    pose[e] = offs[d] + p;
  }
}

// ---------------- edge softmax ----------------

__global__ void selfinit_kernel(const float* __restrict__ as1, const float* __restrict__ ad1,
                                const float* __restrict__ as2, const float* __restrict__ ad2,
                                float* __restrict__ self1, float* __restrict__ self2,
                                unsigned* __restrict__ m1e, unsigned* __restrict__ m2e, int N){
  int i = blockIdx.x * 256 + threadIdx.x;
  if (i >= N) return;
  float e1 = leaky(as1[i] + ad1[i]);
  float e2 = leaky(as2[i] + ad2[i]);
  self1[i] = e1; self2[i] = e2;
  m1e[i] = encf(e1); m2e[i] = encf(e2);
}

__global__ void edgemax_kernel(const int* __restrict__ src, const int* __restrict__ dst,
                               const float* __restrict__ as1, const float* __restrict__ ad1,
                               const float* __restrict__ as2, const float* __restrict__ ad2,
                               unsigned* m1e, unsigned* m2e, int E){
  int e = blockIdx.x * 256 + threadIdx.x;
  if (e >= E) return;
  int s = src[e], d = dst[e];
  atomicMax(&m1e[d], encf(leaky(as1[s] + ad1[d])));
  atomicMax(&m2e[d], encf(leaky(as2[s] + ad2[d])));
}

__global__ void denominit_kernel(const unsigned* __restrict__ m1e, const unsigned* __restrict__ m2e,
                                 const float* __restrict__ self1, const float* __restrict__ self2,
                                 float* __restrict__ m1, float* __restrict__ m2,
                                 float* __restrict__ den1, float* __restrict__ den2, int N){
  int i = blockIdx.x * 256 + threadIdx.x;
  if (i >= N) return;
  float a = decf(m1e[i]), b = decf(m2e[i]);
  m1[i] = a; m2[i] = b;
  den1[i] = expf(self1[i] - a);
  den2[i] = expf(self2[i] - b);
}

// writes CSR-ordered nsrc/nw1/nw2 so agg reads are streaming
__global__ void edgeexp_kernel(const int* __restrict__ src, const int* __restrict__ dst,
                               const float* __restrict__ as1, const float* __restrict__ ad1,
                               const float* __restrict__ as2, const float* __restrict__ ad2,
                               const float* __restrict__ m1, const float* __restrict__ m2,
                               const int* __restrict__ pose,
                               int* __restrict__ nsrc, float* __restrict__ nw1, float* __restrict__ nw2,
                               float* den1, float* den2, int E){
  int e = blockIdx.x * 256 + threadIdx.x;
  if (e >= E) return;
  int s = src[e], d = dst[e];
  float x1 = expf(leaky(as1[s] + ad1[d]) - m1[d]);
  float x2 = expf(leaky(as2[s] + ad2[d]) - m2[d]);
  int p = pose[e];
  nsrc[p] = s; nw1[p] = x1; nw2[p] = x2;
  atomicAdd(&den1[d], x1);
  atomicAdd(&den2[d], x2);
}

// ---------------- GEMM1: H[M][2048] = x_bf16[M][512] @ WcatT[2048][512]^T ----------------
// global_load_lds width-16 staging (m97 pattern): unpadded LDS tile, wave-contiguous layout.

__global__ __launch_bounds__(256) void gemm1_kernel(const unsigned short* __restrict__ A,
                                                    const unsigned short* __restrict__ BT,
                                                    unsigned short* __restrict__ H, int M){
  __shared__ unsigned short Al[128 * 32];
  __shared__ unsigned short Bl[128 * 32];
  const int t = threadIdx.x;
  const int lane = t & 63, wid = t >> 6;
  const int wi = wid & 1, wj = wid >> 1;
  const int l16 = lane & 15, q = lane >> 4;
  const int bm = blockIdx.y * 128, bn = blockIdx.x * 128;
  const int lrow = lane >> 2;            // 0..15 within a 16-row wave issue
  const int lch = (lane & 3) * 8;        // element offset of 16B chunk
  f32x4 acc[4][4] = {};
  for (int k0 = 0; k0 < IN_C; k0 += 32){
    int r0 = wid * 32 + lrow;
    int r1 = r0 + 16;
    int ga0 = min(bm + r0, M - 1);
    int ga1 = min(bm + r1, M - 1);
    GLOAD_LDS16(A + (size_t)ga0 * IN_C + k0 + lch, &Al[(wid * 32) * 32]);
    GLOAD_LDS16(A + (size_t)ga1 * IN_C + k0 + lch, &Al[(wid * 32 + 16) * 32]);
    GLOAD_LDS16(BT + (size_t)(bn + r0) * IN_C + k0 + lch, &Bl[(wid * 32) * 32]);
    GLOAD_LDS16(BT + (size_t)(bn + r1) * IN_C + k0 + lch, &Bl[(wid * 32 + 16) * 32]);
    __syncthreads();
    frag8 af[4], bf[4];
#pragma unroll
    for (int mi = 0; mi < 4; mi++) af[mi] = *(const frag8*)&Al[(wi*64 + mi*16 + l16) * 32 + q*8];
#pragma unroll
    for (int nj = 0; nj < 4; nj++) bf[nj] = *(const frag8*)&Bl[(wj*64 + nj*16 + l16) * 32 + q*8];
#pragma unroll
    for (int mi = 0; mi < 4; mi++)
#pragma unroll
      for (int nj = 0; nj < 4; nj++)
        acc[mi][nj] = __builtin_amdgcn_mfma_f32_16x16x32_bf16(af[mi], bf[nj], acc[mi][nj], 0, 0, 0);
    __syncthreads();
  }
#pragma unroll
  for (int mi = 0; mi < 4; mi++){
#pragma unroll
    for (int r = 0; r < 4; r++){
      int row = bm + wi*64 + mi*16 + q*4 + r;
      if (row >= M) continue;
#pragma unroll
      for (int nj = 0; nj < 4; nj++){
        int col = bn + wj*64 + nj*16 + l16;
        H[(size_t)row * NC2 + col] = f2b(acc[mi][nj][r]);
      }
    }
  }
}

// ---------------- GEMM2: colsum += sum_rows tanh(hsum @ Wp1 + bp1) ----------------

__global__ __launch_bounds__(256) void gemm2_kernel(const unsigned short* __restrict__ A,
                                                    const unsigned short* __restrict__ BT,
                                                    const float* __restrict__ bp1,
                                                    float* __restrict__ colsum, int M){
  __shared__ unsigned short Al[128 * 32];
  __shared__ unsigned short Bl[128 * 32];
  __shared__ float cs[128];
  const int t = threadIdx.x;
  const int lane = t & 63, wid = t >> 6;
  const int wi = wid & 1, wj = wid >> 1;
  const int l16 = lane & 15, q = lane >> 4;
  const int bm = blockIdx.y * 128, bn = blockIdx.x * 128;
  const int lrow = lane >> 2;
  const int lch = (lane & 3) * 8;
  if (t < 128) cs[t] = 0.f;
  f32x4 acc[4][4] = {};
  for (int k0 = 0; k0 < OUT_C; k0 += 32){
    int r0 = wid * 32 + lrow;
    int r1 = r0 + 16;
    int ga0 = min(bm + r0, M - 1);
    int ga1 = min(bm + r1, M - 1);
    GLOAD_LDS16(A + (size_t)ga0 * OUT_C + k0 + lch, &Al[(wid * 32) * 32]);
    GLOAD_LDS16(A + (size_t)ga1 * OUT_C + k0 + lch, &Al[(wid * 32 + 16) * 32]);
    GLOAD_LDS16(BT + (size_t)(bn + r0) * OUT_C + k0 + lch, &Bl[(wid * 32) * 32]);
    GLOAD_LDS16(BT + (size_t)(bn + r1) * OUT_C + k0 + lch, &Bl[(wid * 32 + 16) * 32]);
    __syncthreads();
    frag8 af[4], bf[4];
#pragma unroll
    for (int mi = 0; mi < 4; mi++) af[mi] = *(const frag8*)&Al[(wi*64 + mi*16 + l16) * 32 + q*8];
#pragma unroll
    for (int nj = 0; nj < 4; nj++) bf[nj] = *(const frag8*)&Bl[(wj*64 + nj*16 + l16) * 32 + q*8];
#pragma unroll
    for (int mi = 0; mi < 4; mi++)
#pragma unroll
      for (int nj = 0; nj < 4; nj++)
        acc[mi][nj] = __builtin_amdgcn_mfma_f32_16x16x32_bf16(af[mi], bf[nj], acc[mi][nj], 0, 0, 0);
    __syncthreads();
  }
#pragma unroll
  for (int nj = 0; nj < 4; nj++){
    int col = bn + wj*64 + nj*16 + l16;
    float bias = bp1[col];
    float p = 0.f;
#pragma unroll
    for (int mi = 0; mi < 4; mi++){
#pragma unroll
      for (int r = 0; r < 4; r++){
        int row = bm + wi*64 + mi*16 + q*4 + r;
        float tv = tanhf(acc[mi][nj][r] + bias);
        if (row < M) p += tv;
      }
    }
    p += __shfl_xor(p, 16);
    p += __shfl_xor(p, 32);
    if (q == 0) atomicAdd(&cs[wj*64 + nj*16 + l16], p);
  }
  __syncthreads();
  if (t < 128) atomicAdd(&colsum[bn + t], cs[t]);
}

// ---------------- aggregation: column-sliced for L2 residency ----------------
// grid (N/8, NSLICE=8); block 256 = 8 groups x 32 lanes; group g -> dst d, slice s -> cols [s*128, s*128+128)
// per-slice H working set = N*128*2arrays*2B = 5 MB ~ per-XCD L2.

__global__ __launch_bounds__(256) void agg_kernel(
    const int* __restrict__ counts, const int* __restrict__ offs,
    const int* __restrict__ nsrc, const float* __restrict__ nw1, const float* __restrict__ nw2,
    const float* __restrict__ den1, const float* __restrict__ den2,
    const float* __restrict__ self1, const float* __restrict__ self2,
    const float* __restrict__ m1, const float* __restrict__ m2,
    const unsigned short* __restrict__ H,
    const float* __restrict__ b1, const float* __restrict__ b2, const float* __restrict__ prelu_a,
    float* __restrict__ hout1, float* __restrict__ hout2, unsigned short* __restrict__ hsum, int N){
  int tid = threadIdx.x;
  int g = tid >> 5, lane = tid & 31;
  int grpbase = tid & 32;                 // shuffle base within the 64-lane wave
  int d = blockIdx.x * 8 + g;
  if (d >= N) return;
  int slice = blockIdx.y;
  int colbase = slice * 128 + lane * 4;   // h1 col; h2 at +1024
  float inv1 = 1.f / den1[d], inv2 = 1.f / den2[d];
  int deg = counts[d], off = offs[d];
  float acc1[4] = {0,0,0,0}, acc2[4] = {0,0,0,0};
  for (int base = 0; base < deg; base += 32){
    int i = base + lane;
    int s = 0; float w1 = 0.f, w2 = 0.f;
    if (i < deg){
      int p = off + i;
      s = nsrc[p];
      w1 = nw1[p] * inv1;
      w2 = nw2[p] * inv2;
    }
    int cnt = min(32, deg - base);
    for (int j = 0; j < cnt; j++){
      int sj = __shfl(s, grpbase + j);
      float w1j = __shfl(w1, grpbase + j);
      float w2j = __shfl(w2, grpbase + j);
      const unsigned short* hp = H + (size_t)sj * NC2 + colbase;
      ushort4 u1 = *(const ushort4*)hp;
      ushort4 u2 = *(const ushort4*)(hp + OUT_C);
      acc1[0] += w1j * b2f(u1.x); acc1[1] += w1j * b2f(u1.y);
      acc1[2] += w1j * b2f(u1.z); acc1[3] += w1j * b2f(u1.w);
      acc2[0] += w2j * b2f(u2.x); acc2[1] += w2j * b2f(u2.y);
      acc2[2] += w2j * b2f(u2.z); acc2[3] += w2j * b2f(u2.w);
    }
  }
  // self loop
  {
    float ws1 = expf(self1[d] - m1[d]) * inv1;
    float ws2 = expf(self2[d] - m2[d]) * inv2;
    const unsigned short* hp = H + (size_t)d * NC2 + colbase;
    ushort4 u1 = *(const ushort4*)hp;
    ushort4 u2 = *(const ushort4*)(hp + OUT_C);
    acc1[0] += ws1 * b2f(u1.x); acc1[1] += ws1 * b2f(u1.y);
    acc1[2] += ws1 * b2f(u1.z); acc1[3] += ws1 * b2f(u1.w);
    acc2[0] += ws2 * b2f(u2.x); acc2[1] += ws2 * b2f(u2.y);
    acc2[2] += ws2 * b2f(u2.z); acc2[3] += ws2 * b2f(u2.w);
  }
  float pa = prelu_a[0];
  float4 bb1 = *(const float4*)(b1 + colbase);
  float4 bb2 = *(const float4*)(b2 + colbase);
  float o1[4], o2[4];
  o1[0] = acc1[0] + bb1.x; o1[1] = acc1[1] + bb1.y; o1[2] = acc1[2] + bb1.z; o1[3] = acc1[3] + bb1.w;
  o2[0] = acc2[0] + bb2.x; o2[1] = acc2[1] + bb2.y; o2[2] = acc2[2] + bb2.z; o2[3] = acc2[3] + bb2.w;
#pragma unroll
  for (int r = 0; r < 4; r++){
    o1[r] = o1[r] >= 0.f ? o1[r] : pa * o1[r];
    o2[r] = o2[r] >= 0.f ? o2[r] : pa * o2[r];
  }
  size_t outb = (size_t)d * OUT_C + colbase;
  float4 f1; f1.x = o1[0]; f1.y = o1[1]; f1.z = o1[2]; f1.w = o1[3];
  float4 f2v; f2v.x = o2[0]; f2v.y = o2[1]; f2v.z = o2[2]; f2v.w = o2[3];
  *(float4*)(hout1 + outb) = f1;
  *(float4*)(hout2 + outb) = f2v;
  ushort4 hs;
  hs.x = f2b(o1[0] + o2[0]); hs.y = f2b(o1[1] + o2[1]);
  hs.z = f2b(o1[2] + o2[2]); hs.w = f2b(o1[3] + o2[3]);
  *(ushort4*)(hsum + outb) = hs;
}

// ---------------- semantic attention tail ----------------

__global__ void wproj_kernel(const float* __restrict__ colsum, const float* __restrict__ Wp2,
                             float* __restrict__ wv, float invN){
  int o = blockIdx.x * 256 + threadIdx.x;
  float acc = 0.f;
  for (int c = 0; c < OUT_C; c++) acc += colsum[c] * Wp2[(size_t)c * OUT_C + o];
  wv[o] = acc * invN;
}

__global__ __launch_bounds__(1024) void softmax_kernel(const float* __restrict__ wv, float* __restrict__ att){
  int o = threadIdx.x;
  __shared__ float red[1024];
  float w = wv[o];
  red[o] = w; __syncthreads();
  for (int s = 512; s > 0; s >>= 1){ if (o < s) red[o] = fmaxf(red[o], red[o + s]); __syncthreads(); }
  float m = red[0]; __syncthreads();
  float e = expf(w - m);
  red[o] = e; __syncthreads();
  for (int s = 512; s > 0; s >>= 1){ if (o < s) red[o] += red[o + s]; __syncthreads(); }
  att[o] = e / red[0];
}

__global__ void combine_kernel(const float* __restrict__ att, const float* h1,
                               const float* __restrict__ h2, float* out, int total4){
  int i = blockIdx.x * 256 + threadIdx.x;
  if (i >= total4) return;
  float4 a = ((const float4*)att)[i & 255];
  float4 v1 = ((const float4*)h1)[i];
  float4 v2 = ((const float4*)h2)[i];
  float4 o;
  o.x = a.x * v1.x + (1.f - a.x) * v2.x;
  o.y = a.y * v1.y + (1.f - a.y) * v2.y;
  o.z = a.z * v1.z + (1.f - a.z) * v2.z;
  o.w = a.w * v1.w + (1.f - a.w) * v2.w;
  ((float4*)out)[i] = o;
}

// ---------------- launch ----------------

extern "C" void kernel_launch(void* const* d_in, const int* in_sizes, int n_in,
                              void* d_out, int out_size, void* d_ws, size_t ws_size,
                              hipStream_t stream){
  const float* x      = (const float*)d_in[0];
  const int*   edge   = (const int*)d_in[1];
  const float* W1     = (const float*)d_in[2];
  const float* a_src1 = (const float*)d_in[3];
  const float* a_dst1 = (const float*)d_in[4];
  const float* b1     = (const float*)d_in[5];
  const float* W2     = (const float*)d_in[6];
  const float* a_src2 = (const float*)d_in[7];
  const float* a_dst2 = (const float*)d_in[8];
  const float* b2     = (const float*)d_in[9];
  const float* prelu_a= (const float*)d_in[10];
  const float* Wp1    = (const float*)d_in[11];
  const float* bp1    = (const float*)d_in[12];
  const float* Wp2    = (const float*)d_in[13];
  const int N = in_sizes[0] / IN_C;
  const int E = in_sizes[1] / 2;
  const int* srcArr = edge;
  const int* dstArr = edge + E;

  char* ws = (char*)d_ws;
  size_t o = 0;
  auto alloc = [&](size_t b) -> char* {
    char* p = ws + o;
    o = (o + b + 255) & ~(size_t)255;
    return p;
  };
  unsigned short* xb    = (unsigned short*)alloc((size_t)N * IN_C * 2);
  unsigned short* WT    = (unsigned short*)alloc((size_t)NC2 * IN_C * 2);
  unsigned short* Wp1T  = (unsigned short*)alloc((size_t)OUT_C * OUT_C * 2);
  unsigned short* H     = (unsigned short*)alloc((size_t)N * NC2 * 2);
  float*          hout2 = (float*)alloc((size_t)N * OUT_C * 4);
  unsigned short* hsum  = (unsigned short*)alloc((size_t)N * OUT_C * 2);
  float*          uv    = (float*)alloc(4 * IN_C * 4);
  float*          as1   = (float*)alloc((size_t)4 * N * 4);
  float* ad1 = as1 + N; float* as2 = as1 + 2 * N; float* ad2 = as1 + 3 * N;
  float*          self1 = (float*)alloc((size_t)2 * N * 4); float* self2 = self1 + N;
  unsigned*       m1e   = (unsigned*)alloc((size_t)2 * N * 4); unsigned* m2e = m1e + N;
  float*          m1    = (float*)alloc((size_t)2 * N * 4); float* m2 = m1 + N;
  float*          den1  = (float*)alloc((size_t)2 * N * 4); float* den2 = den1 + N;
  int*            counts= (int*)alloc((size_t)N * 4);
  int*            offs  = (int*)alloc((size_t)(N + 1) * 4);
  int*            cursor= (int*)alloc((size_t)N * 4);
  int*            pose  = (int*)alloc((size_t)E * 4);
  int*            nsrc  = (int*)alloc((size_t)E * 4);
  float*          nw1   = (float*)alloc((size_t)E * 4);
  float*          nw2   = (float*)alloc((size_t)E * 4);
  float*          colsum= (float*)alloc(OUT_C * 4);
  float*          wv    = (float*)alloc(OUT_C * 4);
  float*          att   = (float*)alloc(OUT_C * 4);
  float* hout1 = (float*)d_out;

  dim3 tb(32, 8);
  cvt_x_kernel<<<(N * IN_C / 4 + 255) / 256, 256, 0, stream>>>(x, xb, N * IN_C / 4);
  transpose_cvt_kernel<<<dim3(OUT_C / 32, IN_C / 32), tb, 0, stream>>>(W1, WT, IN_C, OUT_C, 0);
  transpose_cvt_kernel<<<dim3(OUT_C / 32, IN_C / 32), tb, 0, stream>>>(W2, WT, IN_C, OUT_C, OUT_C);
  transpose_cvt_kernel<<<dim3(OUT_C / 32, OUT_C / 32), tb, 0, stream>>>(Wp1, Wp1T, OUT_C, OUT_C, 0);
  uv_kernel<<<512, 256, 0, stream>>>(W1, W2, a_src1, a_dst1, a_src2, a_dst2, uv);
  alpha_kernel<<<N, 256, 0, stream>>>(x, uv, as1, ad1, as2, ad2);
  zero_kernel<<<(N + 255) / 256, 256, 0, stream>>>(counts, cursor, colsum, N);
  hist_kernel<<<(E + 255) / 256, 256, 0, stream>>>(dstArr, counts, E);
  scan_kernel<<<1, 256, 0, stream>>>(counts, offs, N);
  scatter_kernel<<<(E + 255) / 256, 256, 0, stream>>>(dstArr, offs, cursor, pose, E);
  selfinit_kernel<<<(N + 255) / 256, 256, 0, stream>>>(as1, ad1, as2, ad2, self1, self2, m1e, m2e, N);
  edgemax_kernel<<<(E + 255) / 256, 256, 0, stream>>>(srcArr, dstArr, as1, ad1, as2, ad2, m1e, m2e, E);
  denominit_kernel<<<(N + 255) / 256, 256, 0, stream>>>(m1e, m2e, self1, self2, m1, m2, den1, den2, N);
  edgeexp_kernel<<<(E + 255) / 256, 256, 0, stream>>>(srcArr, dstArr, as1, ad1, as2, ad2, m1, m2,
                                                      pose, nsrc, nw1, nw2, den1, den2, E);
  gemm1_kernel<<<dim3(NC2 / 128, (N + 127) / 128), 256, 0, stream>>>(xb, WT, H, N);
  agg_kernel<<<dim3((N + 7) / 8, 8), 256, 0, stream>>>(counts, offs, nsrc, nw1, nw2, den1, den2,
                                                       self1, self2, m1, m2, H, b1, b2, prelu_a,
                                                       hout1, hout2, hsum, N);
  gemm2_kernel<<<dim3(OUT_C / 128, (N + 127) / 128), 256, 0, stream>>>(hsum, Wp1T, bp1, colsum, N);
  wproj_kernel<<<4, 256, 0, stream>>>(colsum, Wp2, wv, 1.0f / (float)N);
  softmax_kernel<<<1, 1024, 0, stream>>>(wv, att);
  combine_kernel<<<(N * OUT_C / 4 + 255) / 256, 256, 0, stream>>>(att, hout1, hout2, (float*)d_out, N * OUT_C / 4);
}

// Round 3
// 401.334 us; speedup vs baseline: 1.2723x; 1.1941x over previous
//
#include <hip/hip_runtime.h>

#define IN_C 512
#define OUT_C 1024
#define NC2 2048
#define NEG_SLOPE 0.2f

typedef short frag8 __attribute__((ext_vector_type(8)));
typedef float f32x4 __attribute__((ext_vector_type(4)));

#define GLOAD_LDS16(g, l) __builtin_amdgcn_global_load_lds(\
    (const __attribute__((address_space(1))) void*)(g), \
    (__attribute__((address_space(3))) void*)(l), 16, 0, 0)

__device__ __forceinline__ unsigned short f2b(float f){
  unsigned u = __float_as_uint(f);
  unsigned r = (u + 0x7fffu + ((u >> 16) & 1u)) >> 16;
  return (unsigned short)r;
}
__device__ __forceinline__ float b2f(unsigned short s){
  return __uint_as_float(((unsigned)s) << 16);
}
__device__ __forceinline__ unsigned encf(float f){
  unsigned u = __float_as_uint(f);
  return (u & 0x80000000u) ? ~u : (u | 0x80000000u);
}
__device__ __forceinline__ float decf(unsigned u){
  unsigned v = (u & 0x80000000u) ? (u & 0x7fffffffu) : ~u;
  return __uint_as_float(v);
}
__device__ __forceinline__ float leaky(float v){ return v >= 0.f ? v : NEG_SLOPE * v; }

// ---------------- conversion / transpose ----------------

__global__ void cvt_x_kernel(const float* __restrict__ x, unsigned short* __restrict__ xb, int total4){
  int i = blockIdx.x * 256 + threadIdx.x;
  if (i >= total4) return;
  float4 v = ((const float4*)x)[i];
  ushort4 o;
  o.x = f2b(v.x); o.y = f2b(v.y); o.z = f2b(v.z); o.w = f2b(v.w);
  ((ushort4*)xb)[i] = o;
}

__global__ void transpose_cvt_kernel(const float* __restrict__ in, unsigned short* __restrict__ out,
                                     int R, int C, int rowOff){
  __shared__ float tile[32][33];
  int c0 = blockIdx.x * 32, r0 = blockIdx.y * 32;
  for (int i = threadIdx.y; i < 32; i += 8)
    tile[i][threadIdx.x] = in[(size_t)(r0 + i) * C + c0 + threadIdx.x];
  __syncthreads();
  for (int i = threadIdx.y; i < 32; i += 8)
    out[(size_t)(c0 + i + rowOff) * R + r0 + threadIdx.x] = f2b(tile[threadIdx.x][i]);
}

// ---------------- attention-logit precompute ----------------

__global__ void uv_kernel(const float* __restrict__ W1, const float* __restrict__ W2,
                          const float* __restrict__ a_src1, const float* __restrict__ a_dst1,
                          const float* __restrict__ a_src2, const float* __restrict__ a_dst2,
                          float* __restrict__ uv){
  int g = blockIdx.x * 4 + (threadIdx.x >> 6);
  int lane = threadIdx.x & 63;
  int which = g >> 9;
  int i = g & 511;
  const float* W = (which < 2) ? W1 : W2;
  const float* a = (which == 0) ? a_src1 : (which == 1) ? a_dst1 : (which == 2) ? a_src2 : a_dst2;
  const float* row = W + (size_t)i * OUT_C;
  float s = 0.f;
  for (int j = lane; j < OUT_C; j += 64) s += row[j] * a[j];
  for (int off = 32; off; off >>= 1) s += __shfl_down(s, off);
  if (lane == 0) uv[which * IN_C + i] = s;
}

// alpha + fused selfinit
__global__ void alpha_kernel(const float* __restrict__ x, const float* __restrict__ uv,
                             float* __restrict__ as1, float* __restrict__ ad1,
                             float* __restrict__ as2, float* __restrict__ ad2,
                             float* __restrict__ self1, float* __restrict__ self2,
                             unsigned* __restrict__ m1e, unsigned* __restrict__ m2e){
  int n = blockIdx.x;
  int w = threadIdx.x >> 6, lane = threadIdx.x & 63;
  __shared__ float sh[4];
  const float* row = x + (size_t)n * IN_C;
  const float* u = uv + w * IN_C;
  float s = 0.f;
  for (int j = lane; j < IN_C; j += 64) s += row[j] * u[j];
  for (int off = 32; off; off >>= 1) s += __shfl_down(s, off);
  if (lane == 0){
    sh[w] = s;
    if (w == 0) as1[n] = s;
    else if (w == 1) ad1[n] = s;
    else if (w == 2) as2[n] = s;
    else ad2[n] = s;
  }
  __syncthreads();
  if (threadIdx.x == 0){
    float e1 = leaky(sh[0] + sh[1]);
    float e2 = leaky(sh[2] + sh[3]);
    self1[n] = e1; self2[n] = e2;
    m1e[n] = encf(e1); m2e[n] = encf(e2);
  }
}

// ---------------- CSR build ----------------

__global__ void zero_kernel(int* counts, int* cursor, float* colsum, float* wv, int N){
  int i = blockIdx.x * 256 + threadIdx.x;
  if (i < N){ counts[i] = 0; cursor[i] = 0; }
  if (i < OUT_C){ colsum[i] = 0.f; wv[i] = 0.f; }
}

__global__ void hist_kernel(const int* __restrict__ dst, int* counts, int E){
  int e = blockIdx.x * 256 + threadIdx.x;
  if (e < E) atomicAdd(&counts[dst[e]], 1);
}

// shfl-based single-block scan
__global__ void scan_kernel(const int* __restrict__ counts, int* __restrict__ offs, int n){
  __shared__ int wsum[4];
  int tid = threadIdx.x;
  int wave = tid >> 6, lane = tid & 63;
  int carry = 0;
  for (int base = 0; base < n; base += 256){
    int i = base + tid;
    int v = (i < n) ? counts[i] : 0;
    int sc = v;
    for (int o = 1; o < 64; o <<= 1){
      int t = __shfl_up(sc, o);
      if (lane >= o) sc += t;
    }
    if (lane == 63) wsum[wave] = sc;
    __syncthreads();
    int wp = 0, tot = 0;
#pragma unroll
    for (int k = 0; k < 4; k++){
      int ws = wsum[k];
      if (k < wave) wp += ws;
      tot += ws;
    }
    if (i < n) offs[i] = carry + wp + sc - v;
    carry += tot;
    __syncthreads();
  }
}

__global__ void scatter_kernel(const int* __restrict__ dst, const int* __restrict__ offs,
                               int* cursor, int* __restrict__ pose, int E){
  int e = blockIdx.x * 256 + threadIdx.x;
  if (e < E){
    int d = dst[e];
    int p = atomicAdd(&cursor[d], 1);
    pose[e] = offs[d] + p;
  }
}

// ---------------- edge softmax ----------------

__global__ void edgemax_kernel(const int* __restrict__ src, const int* __restrict__ dst,
                               const float* __restrict__ as1, const float* __restrict__ ad1,
                               const float* __restrict__ as2, const float* __restrict__ ad2,
                               unsigned* m1e, unsigned* m2e, int E){
  int e = blockIdx.x * 256 + threadIdx.x;
  if (e >= E) return;
  int s = src[e], d = dst[e];
  atomicMax(&m1e[d], encf(leaky(as1[s] + ad1[d])));
  atomicMax(&m2e[d], encf(leaky(as2[s] + ad2[d])));
}

__global__ void denominit_kernel(const unsigned* __restrict__ m1e, const unsigned* __restrict__ m2e,
                                 const float* __restrict__ self1, const float* __restrict__ self2,
                                 float* __restrict__ m1, float* __restrict__ m2,
                                 float* __restrict__ den1, float* __restrict__ den2, int N){
  int i = blockIdx.x * 256 + threadIdx.x;
  if (i >= N) return;
  float a = decf(m1e[i]), b = decf(m2e[i]);
  m1[i] = a; m2[i] = b;
  den1[i] = expf(self1[i] - a);
  den2[i] = expf(self2[i] - b);
}

__global__ void edgeexp_kernel(const int* __restrict__ src, const int* __restrict__ dst,
                               const float* __restrict__ as1, const float* __restrict__ ad1,
                               const float* __restrict__ as2, const float* __restrict__ ad2,
                               const float* __restrict__ m1, const float* __restrict__ m2,
                               const int* __restrict__ pose,
                               int* __restrict__ nsrc, float* __restrict__ nw1, float* __restrict__ nw2,
                               float* den1, float* den2, int E){
  int e = blockIdx.x * 256 + threadIdx.x;
  if (e >= E) return;
  int s = src[e], d = dst[e];
  float x1 = expf(leaky(as1[s] + ad1[d]) - m1[d]);
  float x2 = expf(leaky(as2[s] + ad2[d]) - m2[d]);
  int p = pose[e];
  nsrc[p] = s; nw1[p] = x1; nw2[p] = x2;
  atomicAdd(&den1[d], x1);
  atomicAdd(&den2[d], x2);
}

// ---------------- GEMM1 ----------------

__global__ __launch_bounds__(256) void gemm1_kernel(const unsigned short* __restrict__ A,
                                                    const unsigned short* __restrict__ BT,
                                                    unsigned short* __restrict__ H, int M){
  __shared__ unsigned short Al[128 * 32];
  __shared__ unsigned short Bl[128 * 32];
  const int t = threadIdx.x;
  const int lane = t & 63, wid = t >> 6;
  const int wi = wid & 1, wj = wid >> 1;
  const int l16 = lane & 15, q = lane >> 4;
  const int bm = blockIdx.y * 128, bn = blockIdx.x * 128;
  const int lrow = lane >> 2;
  const int lch = (lane & 3) * 8;
  f32x4 acc[4][4] = {};
  for (int k0 = 0; k0 < IN_C; k0 += 32){
    int r0 = wid * 32 + lrow;
    int r1 = r0 + 16;
    int ga0 = min(bm + r0, M - 1);
    int ga1 = min(bm + r1, M - 1);
    GLOAD_LDS16(A + (size_t)ga0 * IN_C + k0 + lch, &Al[(wid * 32) * 32]);
    GLOAD_LDS16(A + (size_t)ga1 * IN_C + k0 + lch, &Al[(wid * 32 + 16) * 32]);
    GLOAD_LDS16(BT + (size_t)(bn + r0) * IN_C + k0 + lch, &Bl[(wid * 32) * 32]);
    GLOAD_LDS16(BT + (size_t)(bn + r1) * IN_C + k0 + lch, &Bl[(wid * 32 + 16) * 32]);
    __syncthreads();
    frag8 af[4], bf[4];
#pragma unroll
    for (int mi = 0; mi < 4; mi++) af[mi] = *(const frag8*)&Al[(wi*64 + mi*16 + l16) * 32 + q*8];
#pragma unroll
    for (int nj = 0; nj < 4; nj++) bf[nj] = *(const frag8*)&Bl[(wj*64 + nj*16 + l16) * 32 + q*8];
#pragma unroll
    for (int mi = 0; mi < 4; mi++)
#pragma unroll
      for (int nj = 0; nj < 4; nj++)
        acc[mi][nj] = __builtin_amdgcn_mfma_f32_16x16x32_bf16(af[mi], bf[nj], acc[mi][nj], 0, 0, 0);
    __syncthreads();
  }
#pragma unroll
  for (int mi = 0; mi < 4; mi++){
#pragma unroll
    for (int r = 0; r < 4; r++){
      int row = bm + wi*64 + mi*16 + q*4 + r;
      if (row >= M) continue;
#pragma unroll
      for (int nj = 0; nj < 4; nj++){
        int col = bn + wj*64 + nj*16 + l16;
        H[(size_t)row * NC2 + col] = f2b(acc[mi][nj][r]);
      }
    }
  }
}

// ---------------- GEMM2: colsum += sum_rows tanh(hsum @ Wp1 + bp1) ----------------

__global__ __launch_bounds__(256) void gemm2_kernel(const unsigned short* __restrict__ A,
                                                    const unsigned short* __restrict__ BT,
                                                    const float* __restrict__ bp1,
                                                    float* __restrict__ colsum, int M){
  __shared__ unsigned short Al[128 * 32];
  __shared__ unsigned short Bl[128 * 32];
  __shared__ float cs[128];
  const int t = threadIdx.x;
  const int lane = t & 63, wid = t >> 6;
  const int wi = wid & 1, wj = wid >> 1;
  const int l16 = lane & 15, q = lane >> 4;
  const int bm = blockIdx.y * 128, bn = blockIdx.x * 128;
  const int lrow = lane >> 2;
  const int lch = (lane & 3) * 8;
  if (t < 128) cs[t] = 0.f;
  f32x4 acc[4][4] = {};
  for (int k0 = 0; k0 < OUT_C; k0 += 32){
    int r0 = wid * 32 + lrow;
    int r1 = r0 + 16;
    int ga0 = min(bm + r0, M - 1);
    int ga1 = min(bm + r1, M - 1);
    GLOAD_LDS16(A + (size_t)ga0 * OUT_C + k0 + lch, &Al[(wid * 32) * 32]);
    GLOAD_LDS16(A + (size_t)ga1 * OUT_C + k0 + lch, &Al[(wid * 32 + 16) * 32]);
    GLOAD_LDS16(BT + (size_t)(bn + r0) * OUT_C + k0 + lch, &Bl[(wid * 32) * 32]);
    GLOAD_LDS16(BT + (size_t)(bn + r1) * OUT_C + k0 + lch, &Bl[(wid * 32 + 16) * 32]);
    __syncthreads();
    frag8 af[4], bf[4];
#pragma unroll
    for (int mi = 0; mi < 4; mi++) af[mi] = *(const frag8*)&Al[(wi*64 + mi*16 + l16) * 32 + q*8];
#pragma unroll
    for (int nj = 0; nj < 4; nj++) bf[nj] = *(const frag8*)&Bl[(wj*64 + nj*16 + l16) * 32 + q*8];
#pragma unroll
    for (int mi = 0; mi < 4; mi++)
#pragma unroll
      for (int nj = 0; nj < 4; nj++)
        acc[mi][nj] = __builtin_amdgcn_mfma_f32_16x16x32_bf16(af[mi], bf[nj], acc[mi][nj], 0, 0, 0);
    __syncthreads();
  }
#pragma unroll
  for (int nj = 0; nj < 4; nj++){
    int col = bn + wj*64 + nj*16 + l16;
    float bias = bp1[col];
    float p = 0.f;
#pragma unroll
    for (int mi = 0; mi < 4; mi++){
#pragma unroll
      for (int r = 0; r < 4; r++){
        int row = bm + wi*64 + mi*16 + q*4 + r;
        float tv = tanhf(acc[mi][nj][r] + bias);
        if (row < M) p += tv;
      }
    }
    p += __shfl_xor(p, 16);
    p += __shfl_xor(p, 32);
    if (q == 0) atomicAdd(&cs[wj*64 + nj*16 + l16], p);
  }
  __syncthreads();
  if (t < 128) atomicAdd(&colsum[bn + t], cs[t]);
}

// ---------------- aggregation: XCD-pinned column slices ----------------
// grid (8, N/8): slice = blockIdx.x -> XCD (round-robin on linear block id).
// block 256 = 8 groups x 32 lanes; group -> dst node. Within a group:
// lanes 0-15 handle h1, lanes 16-31 handle h2; 8 cols/lane -> 128 cols/slice/array.
// One 16B gather load per edge per lane.

__global__ __launch_bounds__(256) void agg_kernel(
    const int* __restrict__ counts, const int* __restrict__ offs,
    const int* __restrict__ nsrc, const float* __restrict__ nw1, const float* __restrict__ nw2,
    const float* __restrict__ den1, const float* __restrict__ den2,
    const float* __restrict__ self1, const float* __restrict__ self2,
    const float* __restrict__ m1, const float* __restrict__ m2,
    const unsigned short* __restrict__ H,
    const float* __restrict__ b1, const float* __restrict__ b2, const float* __restrict__ prelu_a,
    float* __restrict__ hout1, float* __restrict__ hout2, unsigned short* __restrict__ hsum, int N){
  int tid = threadIdx.x;
  int g = tid >> 5, lane = tid & 31;
  int grpbase = tid & 32;               // group's base within the 64-lane wave
  int half = lane >> 4, hl = lane & 15; // half=0 -> h1, half=1 -> h2
  int d = blockIdx.y * 8 + g;
  if (d >= N) return;
  int slice = blockIdx.x;
  int colbase = slice * 128 + hl * 8;
  float inv = half ? 1.f / den2[d] : 1.f / den1[d];
  float inv1 = 1.f / den1[d], inv2 = 1.f / den2[d];
  int deg = counts[d], off = offs[d];
  float acc[8] = {0,0,0,0,0,0,0,0};
  const unsigned short* Hbase = H + (size_t)half * OUT_C + colbase;
  for (int base = 0; base < deg; base += 32){
    int i = base + lane;
    int s = 0; float w1 = 0.f, w2 = 0.f;
    if (i < deg){
      int p = off + i;
      s = nsrc[p];
      w1 = nw1[p] * inv1;
      w2 = nw2[p] * inv2;
    }
    int cnt = min(32, deg - base);
#pragma unroll 4
    for (int j = 0; j < cnt; j++){
      int sj = __shfl(s, grpbase + j);
      float w1j = __shfl(w1, grpbase + j);
      float w2j = __shfl(w2, grpbase + j);
      float wj = half ? w2j : w1j;
      int4 u = *(const int4*)(Hbase + (size_t)sj * NC2);
      acc[0] += wj * __uint_as_float(((unsigned)u.x) << 16);
      acc[1] += wj * __uint_as_float(((unsigned)u.x) & 0xffff0000u);
      acc[2] += wj * __uint_as_float(((unsigned)u.y) << 16);
      acc[3] += wj * __uint_as_float(((unsigned)u.y) & 0xffff0000u);
      acc[4] += wj * __uint_as_float(((unsigned)u.z) << 16);
      acc[5] += wj * __uint_as_float(((unsigned)u.z) & 0xffff0000u);
      acc[6] += wj * __uint_as_float(((unsigned)u.w) << 16);
      acc[7] += wj * __uint_as_float(((unsigned)u.w) & 0xffff0000u);
    }
  }
  // self loop
  {
    float ws = expf((half ? self2[d] : self1[d]) - (half ? m2[d] : m1[d])) * inv;
    int4 u = *(const int4*)(Hbase + (size_t)d * NC2);
    acc[0] += ws * __uint_as_float(((unsigned)u.x) << 16);
    acc[1] += ws * __uint_as_float(((unsigned)u.x) & 0xffff0000u);
    acc[2] += ws * __uint_as_float(((unsigned)u.y) << 16);
    acc[3] += ws * __uint_as_float(((unsigned)u.y) & 0xffff0000u);
    acc[4] += ws * __uint_as_float(((unsigned)u.z) << 16);
    acc[5] += ws * __uint_as_float(((unsigned)u.z) & 0xffff0000u);
    acc[6] += ws * __uint_as_float(((unsigned)u.w) << 16);
    acc[7] += ws * __uint_as_float(((unsigned)u.w) & 0xffff0000u);
  }
  float pa = prelu_a[0];
  const float* bb = (half ? b2 : b1) + colbase;
  float4 bl0 = *(const float4*)bb;
  float4 bl1 = *(const float4*)(bb + 4);
  float o[8];
  o[0] = acc[0] + bl0.x; o[1] = acc[1] + bl0.y; o[2] = acc[2] + bl0.z; o[3] = acc[3] + bl0.w;
  o[4] = acc[4] + bl1.x; o[5] = acc[5] + bl1.y; o[6] = acc[6] + bl1.z; o[7] = acc[7] + bl1.w;
#pragma unroll
  for (int r = 0; r < 8; r++) o[r] = o[r] >= 0.f ? o[r] : pa * o[r];
  size_t outb = (size_t)d * OUT_C + colbase;
  float* hout = half ? hout2 : hout1;
  float4 f0; f0.x = o[0]; f0.y = o[1]; f0.z = o[2]; f0.w = o[3];
  float4 f1; f1.x = o[4]; f1.y = o[5]; f1.z = o[6]; f1.w = o[7];
  *(float4*)(hout + outb) = f0;
  *(float4*)(hout + outb + 4) = f1;
  // hsum = bf16(o_h1 + o_h2): exchange across halves, lanes of half 0 store
  float oo[8];
#pragma unroll
  for (int r = 0; r < 8; r++) oo[r] = o[r] + __shfl_xor(o[r], 16);
  if (half == 0){
    int4 hs;
    hs.x = (int)((unsigned)f2b(oo[0]) | ((unsigned)f2b(oo[1]) << 16));
    hs.y = (int)((unsigned)f2b(oo[2]) | ((unsigned)f2b(oo[3]) << 16));
    hs.z = (int)((unsigned)f2b(oo[4]) | ((unsigned)f2b(oo[5]) << 16));
    hs.w = (int)((unsigned)f2b(oo[6]) | ((unsigned)f2b(oo[7]) << 16));
    *(int4*)(hsum + outb) = hs;
  }
}

// ---------------- semantic attention tail ----------------

// split-K parallel projection: grid (4, 8); wv must be zeroed first
__global__ void wproj_kernel(const float* __restrict__ colsum, const float* __restrict__ Wp2,
                             float* __restrict__ wv){
  int o = blockIdx.x * 256 + threadIdx.x;
  int c0 = blockIdx.y * 128;
  float acc = 0.f;
  for (int c = c0; c < c0 + 128; c++) acc += colsum[c] * Wp2[(size_t)c * OUT_C + o];
  atomicAdd(&wv[o], acc);
}

__global__ __launch_bounds__(1024) void softmax_kernel(const float* __restrict__ wv,
                                                       float* __restrict__ att, float invN){
  int o = threadIdx.x;
  __shared__ float red[1024];
  float w = wv[o] * invN;
  red[o] = w; __syncthreads();
  for (int s = 512; s > 0; s >>= 1){ if (o < s) red[o] = fmaxf(red[o], red[o + s]); __syncthreads(); }
  float m = red[0]; __syncthreads();
  float e = expf(w - m);
  red[o] = e; __syncthreads();
  for (int s = 512; s > 0; s >>= 1){ if (o < s) red[o] += red[o + s]; __syncthreads(); }
  att[o] = e / red[0];
}

__global__ void combine_kernel(const float* __restrict__ att, const float* h1,
                               const float* __restrict__ h2, float* out, int total4){
  int i = blockIdx.x * 256 + threadIdx.x;
  if (i >= total4) return;
  float4 a = ((const float4*)att)[i & 255];
  float4 v1 = ((const float4*)h1)[i];
  float4 v2 = ((const float4*)h2)[i];
  float4 o;
  o.x = a.x * v1.x + (1.f - a.x) * v2.x;
  o.y = a.y * v1.y + (1.f - a.y) * v2.y;
  o.z = a.z * v1.z + (1.f - a.z) * v2.z;
  o.w = a.w * v1.w + (1.f - a.w) * v2.w;
  ((float4*)out)[i] = o;
}

// ---------------- launch ----------------

extern "C" void kernel_launch(void* const* d_in, const int* in_sizes, int n_in,
                              void* d_out, int out_size, void* d_ws, size_t ws_size,
                              hipStream_t stream){
  const float* x      = (const float*)d_in[0];
  const int*   edge   = (const int*)d_in[1];
  const float* W1     = (const float*)d_in[2];
  const float* a_src1 = (const float*)d_in[3];
  const float* a_dst1 = (const float*)d_in[4];
  const float* b1     = (const float*)d_in[5];
  const float* W2     = (const float*)d_in[6];
  const float* a_src2 = (const float*)d_in[7];
  const float* a_dst2 = (const float*)d_in[8];
  const float* b2     = (const float*)d_in[9];
  const float* prelu_a= (const float*)d_in[10];
  const float* Wp1    = (const float*)d_in[11];
  const float* bp1    = (const float*)d_in[12];
  const float* Wp2    = (const float*)d_in[13];
  const int N = in_sizes[0] / IN_C;
  const int E = in_sizes[1] / 2;
  const int* srcArr = edge;
  const int* dstArr = edge + E;

  char* ws = (char*)d_ws;
  size_t o = 0;
  auto alloc = [&](size_t b) -> char* {
    char* p = ws + o;
    o = (o + b + 255) & ~(size_t)255;
    return p;
  };
  unsigned short* xb    = (unsigned short*)alloc((size_t)N * IN_C * 2);
  unsigned short* WT    = (unsigned short*)alloc((size_t)NC2 * IN_C * 2);
  unsigned short* Wp1T  = (unsigned short*)alloc((size_t)OUT_C * OUT_C * 2);
  unsigned short* H     = (unsigned short*)alloc((size_t)N * NC2 * 2);
  float*          hout2 = (float*)alloc((size_t)N * OUT_C * 4);
  unsigned short* hsum  = (unsigned short*)alloc((size_t)N * OUT_C * 2);
  float*          uv    = (float*)alloc(4 * IN_C * 4);
  float*          as1   = (float*)alloc((size_t)4 * N * 4);
  float* ad1 = as1 + N; float* as2 = as1 + 2 * N; float* ad2 = as1 + 3 * N;
  float*          self1 = (float*)alloc((size_t)2 * N * 4); float* self2 = self1 + N;
  unsigned*       m1e   = (unsigned*)alloc((size_t)2 * N * 4); unsigned* m2e = m1e + N;
  float*          m1    = (float*)alloc((size_t)2 * N * 4); float* m2 = m1 + N;
  float*          den1  = (float*)alloc((size_t)2 * N * 4); float* den2 = den1 + N;
  int*            counts= (int*)alloc((size_t)N * 4);
  int*            offs  = (int*)alloc((size_t)(N + 1) * 4);
  int*            cursor= (int*)alloc((size_t)N * 4);
  int*            pose  = (int*)alloc((size_t)E * 4);
  int*            nsrc  = (int*)alloc((size_t)E * 4);
  float*          nw1   = (float*)alloc((size_t)E * 4);
  float*          nw2   = (float*)alloc((size_t)E * 4);
  float*          colsum= (float*)alloc(OUT_C * 4);
  float*          wv    = (float*)alloc(OUT_C * 4);
  float*          att   = (float*)alloc(OUT_C * 4);
  float* hout1 = (float*)d_out;

  dim3 tb(32, 8);
  cvt_x_kernel<<<(N * IN_C / 4 + 255) / 256, 256, 0, stream>>>(x, xb, N * IN_C / 4);
  transpose_cvt_kernel<<<dim3(OUT_C / 32, IN_C / 32), tb, 0, stream>>>(W1, WT, IN_C, OUT_C, 0);
  transpose_cvt_kernel<<<dim3(OUT_C / 32, IN_C / 32), tb, 0, stream>>>(W2, WT, IN_C, OUT_C, OUT_C);
  transpose_cvt_kernel<<<dim3(OUT_C / 32, OUT_C / 32), tb, 0, stream>>>(Wp1, Wp1T, OUT_C, OUT_C, 0);
  uv_kernel<<<512, 256, 0, stream>>>(W1, W2, a_src1, a_dst1, a_src2, a_dst2, uv);
  alpha_kernel<<<N, 256, 0, stream>>>(x, uv, as1, ad1, as2, ad2, self1, self2, m1e, m2e);
  zero_kernel<<<(N + 255) / 256, 256, 0, stream>>>(counts, cursor, colsum, wv, N);
  hist_kernel<<<(E + 255) / 256, 256, 0, stream>>>(dstArr, counts, E);
  scan_kernel<<<1, 256, 0, stream>>>(counts, offs, N);
  scatter_kernel<<<(E + 255) / 256, 256, 0, stream>>>(dstArr, offs, cursor, pose, E);
  edgemax_kernel<<<(E + 255) / 256, 256, 0, stream>>>(srcArr, dstArr, as1, ad1, as2, ad2, m1e, m2e, E);
  denominit_kernel<<<(N + 255) / 256, 256, 0, stream>>>(m1e, m2e, self1, self2, m1, m2, den1, den2, N);
  edgeexp_kernel<<<(E + 255) / 256, 256, 0, stream>>>(srcArr, dstArr, as1, ad1, as2, ad2, m1, m2,
                                                      pose, nsrc, nw1, nw2, den1, den2, E);
  gemm1_kernel<<<dim3(NC2 / 128, (N + 127) / 128), 256, 0, stream>>>(xb, WT, H, N);
  agg_kernel<<<dim3(8, (N + 7) / 8), 256, 0, stream>>>(counts, offs, nsrc, nw1, nw2, den1, den2,
                                                       self1, self2, m1, m2, H, b1, b2, prelu_a,
                                                       hout1, hout2, hsum, N);
  gemm2_kernel<<<dim3(OUT_C / 128, (N + 127) / 128), 256, 0, stream>>>(hsum, Wp1T, bp1, colsum, N);
  wproj_kernel<<<dim3(4, 8), 256, 0, stream>>>(colsum, Wp2, wv);
  softmax_kernel<<<1, 1024, 0, stream>>>(wv, att, 1.0f / (float)N);
  combine_kernel<<<(N * OUT_C / 4 + 255) / 256, 256, 0, stream>>>(att, hout1, hout2, (float*)d_out, N * OUT_C / 4);
}